// Round 1
// baseline (478.949 us; speedup 1.0000x reference)
//
#include <hip/hip_runtime.h>
#include <math.h>
#include <stdint.h>

#define NLEV 16
#define TSIZE (1u << 19)
#define NB 4096
#define NS 48
#define NPTS (NB * NS)

struct Scales { float s[NLEV]; };

__device__ __forceinline__ uint32_t hash3(uint32_t x, uint32_t y, uint32_t z) {
    return (x ^ (y * 2654435761u) ^ (z * 805459861u)) & (TSIZE - 1u);
}

__device__ __forceinline__ float sigmoidf(float v) {
    return 1.0f / (1.0f + expf(-v));
}

// Kernel 1: one thread per (b,s) point. Computes camera transform, hash
// encoding, geo MLP, SH16, rgb MLP; writes rgb (3 floats) to workspace.
// Weights are read with wave-uniform indices from global memory so the
// compiler emits scalar (SMEM) loads; activations live in registers via
// full unroll.
__global__ __launch_bounds__(256) void point_kernel(
    const float* __restrict__ positions,
    const float* __restrict__ normals,
    const float* __restrict__ c2w,
    const float* __restrict__ table,
    const float* __restrict__ w1, const float* __restrict__ b1,
    const float* __restrict__ w2, const float* __restrict__ b2,
    const float* __restrict__ h1, const float* __restrict__ hb1,
    const float* __restrict__ h2, const float* __restrict__ hb2,
    const float* __restrict__ h3, const float* __restrict__ hb3,
    float* __restrict__ rgb_out,
    Scales sc)
{
    const int g = blockIdx.x * blockDim.x + threadIdx.x;
    if (g >= NPTS) return;
    const int b = g / NS;

    // Rotation (row-major 3x4) and translation
    const float* M = c2w + b * 12;
    const float R00 = M[0], R01 = M[1], R02 = M[2],  T0 = M[3];
    const float R10 = M[4], R11 = M[5], R12 = M[6],  T1 = M[7];
    const float R20 = M[8], R21 = M[9], R22 = M[10], T2 = M[11];

    const float px = positions[3 * g + 0];
    const float py = positions[3 * g + 1];
    const float pz = positions[3 * g + 2];

    // pos_cam = R^T (p - t);  pos = (pos_cam + 1) / 2
    const float dx = px - T0, dy = py - T1, dz = pz - T2;
    float qx = R00 * dx + R10 * dy + R20 * dz;
    float qy = R01 * dx + R11 * dy + R21 * dz;
    float qz = R02 * dx + R12 * dy + R22 * dz;
    qx = (qx + 1.0f) * 0.5f;
    qy = (qy + 1.0f) * 0.5f;
    qz = (qz + 1.0f) * 0.5f;
    const bool sel = (qx > 0.0f) && (qx < 1.0f) &&
                     (qy > 0.0f) && (qy < 1.0f) &&
                     (qz > 0.0f) && (qz < 1.0f);
    if (!sel) { qx = 0.0f; qy = 0.0f; qz = 0.0f; }

    // ---- hash-grid encoding: 16 levels x 2 feats ----
    float enc[32];
    const float2* tab2 = (const float2*)table;
#pragma unroll
    for (int l = 0; l < NLEV; ++l) {
        const float s  = sc.s[l];
        const float sx = qx * s, sy = qy * s, sz = qz * s;
        const float fx = floorf(sx), fy = floorf(sy), fz = floorf(sz);
        const float cx = ceilf(sx),  cy = ceilf(sy),  cz = ceilf(sz);
        const float ox = sx - fx, oy = sy - fy, oz = sz - fz;
        const uint32_t fxi = (uint32_t)fx, fyi = (uint32_t)fy, fzi = (uint32_t)fz;
        const uint32_t cxi = (uint32_t)cx, cyi = (uint32_t)cy, czi = (uint32_t)cz;
        const uint32_t base = (uint32_t)l * TSIZE;

        const float2 f0 = tab2[base + hash3(cxi, cyi, czi)];
        const float2 f1 = tab2[base + hash3(cxi, fyi, czi)];
        const float2 f2 = tab2[base + hash3(fxi, fyi, czi)];
        const float2 f3 = tab2[base + hash3(fxi, cyi, czi)];
        const float2 f4 = tab2[base + hash3(cxi, cyi, fzi)];
        const float2 f5 = tab2[base + hash3(cxi, fyi, fzi)];
        const float2 f6 = tab2[base + hash3(fxi, fyi, fzi)];
        const float2 f7 = tab2[base + hash3(fxi, cyi, fzi)];

        const float omx = 1.0f - ox, omy = 1.0f - oy, omz = 1.0f - oz;
        float f03x = f0.x * ox + f3.x * omx, f03y = f0.y * ox + f3.y * omx;
        float f12x = f1.x * ox + f2.x * omx, f12y = f1.y * ox + f2.y * omx;
        float f56x = f5.x * ox + f6.x * omx, f56y = f5.y * ox + f6.y * omx;
        float f47x = f4.x * ox + f7.x * omx, f47y = f4.y * ox + f7.y * omx;
        float a_x = f03x * oy + f12x * omy, a_y = f03y * oy + f12y * omy;
        float b_x = f47x * oy + f56x * omy, b_y = f47y * oy + f56y * omy;
        enc[2 * l + 0] = a_x * oz + b_x * omz;
        enc[2 * l + 1] = a_y * oz + b_y * omz;
    }

    // ---- geo MLP: enc(32) -> 64 -> 16, relu ----
    float a1[64];
#pragma unroll
    for (int j = 0; j < 64; ++j) {
        float acc = b1[j];
#pragma unroll
        for (int i = 0; i < 32; ++i) acc += enc[i] * w1[i * 64 + j];
        a1[j] = fmaxf(acc, 0.0f);
    }
    float geo[16];
#pragma unroll
    for (int j = 0; j < 16; ++j) {
        float acc = b2[j];
#pragma unroll
        for (int i = 0; i < 64; ++i) acc += a1[i] * w2[i * 16 + j];
        geo[j] = fmaxf(acc, 0.0f);
    }

    // ---- SH16 of normalized camera-space normal (computed late to cap regs) ----
    float hvec[32];
    {
        const float n0 = normals[3 * b + 0];
        const float n1 = normals[3 * b + 1];
        const float n2 = normals[3 * b + 2];
        float x = R00 * n0 + R10 * n1 + R20 * n2;
        float y = R01 * n0 + R11 * n1 + R21 * n2;
        float z = R02 * n0 + R12 * n1 + R22 * n2;
        x = (x + 1.0f) * 0.5f;
        y = (y + 1.0f) * 0.5f;
        z = (z + 1.0f) * 0.5f;
        const float xx = x * x, yy = y * y, zz = z * z;
        hvec[0]  = 0.28209479177387814f;
        hvec[1]  = -0.48860251190291987f * y;
        hvec[2]  = 0.48860251190291987f * z;
        hvec[3]  = -0.48860251190291987f * x;
        hvec[4]  = 1.0925484305920792f * x * y;
        hvec[5]  = -1.0925484305920792f * y * z;
        hvec[6]  = 0.94617469575756f * zz - 0.31539156525252f;
        hvec[7]  = -1.0925484305920792f * x * z;
        hvec[8]  = 0.5462742152960396f * (xx - yy);
        hvec[9]  = 0.5900435899266435f * y * (3.0f * xx - yy);
        hvec[10] = 2.890611442640554f * x * y * z;
        hvec[11] = 0.4570457994644657f * y * (5.0f * zz - 1.0f);
        hvec[12] = 0.37317633259011546f * z * (5.0f * zz - 3.0f);
        hvec[13] = 0.4570457994644657f * x * (5.0f * zz - 1.0f);
        hvec[14] = 1.445305721320277f * z * (xx - yy);
        hvec[15] = 0.5900435899266435f * x * (xx - 3.0f * yy);
    }
#pragma unroll
    for (int j = 0; j < 16; ++j) hvec[16 + j] = geo[j];

    // ---- rgb MLP: h(32) -> 64 -> 64 -> 3, relu, sigmoid ----
    float g1[64];
#pragma unroll
    for (int j = 0; j < 64; ++j) {
        float acc = hb1[j];
#pragma unroll
        for (int i = 0; i < 32; ++i) acc += hvec[i] * h1[i * 64 + j];
        g1[j] = fmaxf(acc, 0.0f);
    }
    float g2[64];
#pragma unroll
    for (int j = 0; j < 64; ++j) {
        float acc = hb2[j];
#pragma unroll
        for (int i = 0; i < 64; ++i) acc += g1[i] * h2[i * 64 + j];
        g2[j] = fmaxf(acc, 0.0f);
    }
#pragma unroll
    for (int c = 0; c < 3; ++c) {
        float acc = hb3[c];
#pragma unroll
        for (int i = 0; i < 64; ++i) acc += g2[i] * h3[i * 3 + c];
        rgb_out[3 * g + c] = sigmoidf(acc);
    }
}

// Kernel 2: one 64-thread block per batch. Softmax over S=48 densities,
// weighted sum of rgb -> out[b][3].
__global__ __launch_bounds__(64) void reduce_kernel(
    const float* __restrict__ densities,
    const float* __restrict__ rgb,
    float* __restrict__ out)
{
    const int b = blockIdx.x;
    const int t = threadIdx.x;
    const bool valid = t < NS;

    float d = valid ? densities[b * NS + t] : -INFINITY;
    float m = d;
#pragma unroll
    for (int off = 32; off > 0; off >>= 1) m = fmaxf(m, __shfl_xor(m, off));
    float e = valid ? expf(d - m) : 0.0f;
    float sum = e;
#pragma unroll
    for (int off = 32; off > 0; off >>= 1) sum += __shfl_xor(sum, off);
    const float w = e / sum;

    float r0 = 0.0f, r1 = 0.0f, r2 = 0.0f;
    if (valid) {
        const int base = (b * NS + t) * 3;
        r0 = w * rgb[base + 0];
        r1 = w * rgb[base + 1];
        r2 = w * rgb[base + 2];
    }
#pragma unroll
    for (int off = 32; off > 0; off >>= 1) {
        r0 += __shfl_xor(r0, off);
        r1 += __shfl_xor(r1, off);
        r2 += __shfl_xor(r2, off);
    }
    if (t == 0) {
        out[3 * b + 0] = r0;
        out[3 * b + 1] = r1;
        out[3 * b + 2] = r2;
    }
}

extern "C" void kernel_launch(void* const* d_in, const int* in_sizes, int n_in,
                              void* d_out, int out_size, void* d_ws, size_t ws_size,
                              hipStream_t stream) {
    const float* positions = (const float*)d_in[0];
    const float* densities = (const float*)d_in[1];
    const float* normals   = (const float*)d_in[2];
    const float* c2w       = (const float*)d_in[3];
    const float* table     = (const float*)d_in[4];
    const float* w1  = (const float*)d_in[5];
    const float* b1  = (const float*)d_in[6];
    const float* w2  = (const float*)d_in[7];
    const float* b2  = (const float*)d_in[8];
    const float* h1  = (const float*)d_in[9];
    const float* hb1 = (const float*)d_in[10];
    const float* h2  = (const float*)d_in[11];
    const float* hb2 = (const float*)d_in[12];
    const float* h3  = (const float*)d_in[13];
    const float* hb3 = (const float*)d_in[14];
    float* out = (float*)d_out;
    float* rgb_ws = (float*)d_ws;  // NPTS*3 floats

    // Match numpy: floor(16 * exp((ln 2048 - ln 16)/15)^i), computed in double.
    Scales sc;
    const double growth = exp((log(2048.0) - log(16.0)) / 15.0);
    for (int i = 0; i < NLEV; ++i)
        sc.s[i] = (float)floor(16.0 * pow(growth, (double)i));

    const int threads = 256;
    const int blocks = (NPTS + threads - 1) / threads;
    point_kernel<<<blocks, threads, 0, stream>>>(
        positions, normals, c2w, table,
        w1, b1, w2, b2, h1, hb1, h2, hb2, h3, hb3,
        rgb_ws, sc);
    reduce_kernel<<<NB, 64, 0, stream>>>(densities, rgb_ws, out);
}